// Round 9
// baseline (966.523 us; speedup 1.0000x reference)
//
#include <hip/hip_runtime.h>
#include <cstdint>
#include <cstddef>

// Problem constants (match reference)
constexpr int Nn = 50000;
constexpr int Ne = 500000;
constexpr int Gg = 64;
constexpr int DIN = 128, ED = 32, H1 = 256, H2 = 128, HD = 64, NOUT = 8;

// ---------------- CSR build ----------------
__global__ void count_deg_kernel(const int* __restrict__ dst, int* __restrict__ deg) {
    int e = blockIdx.x * 256 + threadIdx.x;
    if (e < Ne) atomicAdd(&deg[dst[e]], 1);
}

__global__ __launch_bounds__(1024) void scan_kernel(const int* __restrict__ deg,
                                                    int* __restrict__ row_start) {
    __shared__ int part[1024];
    int t = threadIdx.x;
    const int chunk = (Nn + 1023) / 1024;
    int lo = t * chunk;
    int hi = min(lo + chunk, Nn);
    int s = 0;
    for (int i = lo; i < hi; i++) s += deg[i];
    part[t] = s;
    __syncthreads();
    for (int off = 1; off < 1024; off <<= 1) {
        int add = (t >= off) ? part[t - off] : 0;
        __syncthreads();
        part[t] += add;
        __syncthreads();
    }
    int base = (t == 0) ? 0 : part[t - 1];
    for (int i = lo; i < hi; i++) { row_start[i] = base; base += deg[i]; }
    if (t == 0) row_start[Nn] = Ne;
}

__global__ void scatter_kernel(const int* __restrict__ dst, const int* __restrict__ row_start,
                               int* __restrict__ cursor, int* __restrict__ perm) {
    int e = blockIdx.x * 256 + threadIdx.x;
    if (e < Ne) {
        int d = dst[e];
        int p = atomicAdd(&cursor[d], 1);
        perm[row_start[d] + p] = e;
    }
}

__global__ void build_sd_kernel(const int* __restrict__ perm, const int* __restrict__ src,
                                const int* __restrict__ dst,
                                int* __restrict__ srcv, int* __restrict__ dstv) {
    int j = blockIdx.x * 256 + threadIdx.x;
    if (j < Ne) {
        int e = perm[j];
        srcv[j] = src[e];
        dstv[j] = dst[e];
    }
}

// loop_attr[i] = mean of incoming edge_attr rows (self-loop fill_value='mean')
__global__ void loop_attr_kernel(const int* __restrict__ row_start, const int* __restrict__ perm,
                                 const float* __restrict__ eattr, float* __restrict__ loop_attr) {
    int tid = blockIdx.x * 256 + threadIdx.x;
    if (tid >= Nn * 8) return;
    int i = tid >> 3, q = (tid & 7) << 2;
    int r0 = row_start[i], r1 = row_start[i + 1];
    float4 s = make_float4(0.f, 0.f, 0.f, 0.f);
    for (int j = r0; j < r1; j++) {
        int e = perm[j];
        float4 v = *(const float4*)(eattr + (size_t)e * ED + q);
        s.x += v.x; s.y += v.y; s.z += v.z; s.w += v.w;
    }
    float inv = 1.0f / fmaxf((float)(r1 - r0), 1.0f);
    *(float4*)(loop_attr + (size_t)i * ED + q) =
        make_float4(s.x * inv, s.y * inv, s.z * inv, s.w * inv);
}

// ---------------- fp32 GEMM with K-chunk register double-buffer ----------------
__global__ __launch_bounds__(256) void gemm_bias2_kernel(const float* __restrict__ A,
                                                         const float* __restrict__ W0,
                                                         const float* __restrict__ bias0,
                                                         float* __restrict__ C0,
                                                         const float* __restrict__ W1,
                                                         const float* __restrict__ bias1,
                                                         float* __restrict__ C1,
                                                         int M, int K, int Ncols) {
    const float* W = blockIdx.z ? W1 : W0;
    const float* bias = blockIdx.z ? bias1 : bias0;
    float* C = blockIdx.z ? C1 : C0;
    __shared__ float As[16][68];  // [k][m], padded
    __shared__ float Bs[16][68];  // [k][n], padded
    const int m0 = blockIdx.y * 64, n0 = blockIdx.x * 64;
    const int tid = threadIdx.x;
    const int tx = tid & 15, ty = tid >> 4;
    float acc[4][4] = {};
    const int ar = tid >> 2, ac4 = (tid & 3) << 2;
    const int br = tid >> 4, bc4 = (tid & 15) << 2;
    const bool arow_ok = (m0 + ar < M);

    float4 av = make_float4(0.f, 0.f, 0.f, 0.f);
    if (arow_ok) av = *(const float4*)(A + (size_t)(m0 + ar) * K + ac4);
    float4 bv = *(const float4*)(W + (size_t)br * Ncols + n0 + bc4);

    for (int k0 = 0; k0 < K; k0 += 16) {
        As[ac4 + 0][ar] = av.x; As[ac4 + 1][ar] = av.y;
        As[ac4 + 2][ar] = av.z; As[ac4 + 3][ar] = av.w;
        *(float4*)&Bs[br][bc4] = bv;
        __syncthreads();
        // prefetch next chunk behind the FMA loop
        if (k0 + 16 < K) {
            if (arow_ok) av = *(const float4*)(A + (size_t)(m0 + ar) * K + k0 + 16 + ac4);
            bv = *(const float4*)(W + (size_t)(k0 + 16 + br) * Ncols + n0 + bc4);
        }
#pragma unroll
        for (int k = 0; k < 16; k++) {
            float a[4], b[4];
#pragma unroll
            for (int i = 0; i < 4; i++) a[i] = As[k][ty * 4 + i];
#pragma unroll
            for (int j = 0; j < 4; j++) b[j] = Bs[k][tx * 4 + j];
#pragma unroll
            for (int i = 0; i < 4; i++)
#pragma unroll
                for (int j = 0; j < 4; j++) acc[i][j] = fmaf(a[i], b[j], acc[i][j]);
        }
        __syncthreads();
    }
#pragma unroll
    for (int i = 0; i < 4; i++) {
        int m = m0 + ty * 4 + i;
        if (m < M) {
            float4 o;
            o.x = acc[i][0] + bias[n0 + tx * 4 + 0];
            o.y = acc[i][1] + bias[n0 + tx * 4 + 1];
            o.z = acc[i][2] + bias[n0 + tx * 4 + 2];
            o.w = acc[i][3] + bias[n0 + tx * 4 + 3];
            *(float4*)(C + (size_t)m * Ncols + n0 + tx * 4) = o;
        }
    }
}

// ---------------- score GEMM v3: col-tile loop + gather prefetch across tiles ----------
// score[r] = sum_c att[c] * leakyrelu( (attr[r]@We)[c] + xl[s_r][c] + xr[d_r][c] )
template <int C>
__global__ __launch_bounds__(256) void score_gemm3_kernel(
    int count, const int* __restrict__ perm,
    const int* __restrict__ srcv, const int* __restrict__ dstv,
    const float* __restrict__ attr,
    const float* __restrict__ xl, const float* __restrict__ xr,
    const float* __restrict__ We, const float* __restrict__ att,
    float* __restrict__ sc_out) {
    __shared__ float As[32][68];   // eattr^T [k][row]
    __shared__ float Bs[32][68];   // We tile [k][col]
    const int m0 = blockIdx.x * 64;
    const int tid = threadIdx.x, tx = tid & 15, ty = tid >> 4;

    // stage A^T once: 64 rows x 32 k
    {
        int ar = tid >> 2, ac8 = (tid & 3) << 3;
        int row = min(m0 + ar, count - 1);
        int e = perm ? perm[row] : row;
        const float* s = attr + (size_t)e * ED + ac8;
        float4 v0 = *(const float4*)s;
        float4 v1 = *(const float4*)(s + 4);
        As[ac8 + 0][ar] = v0.x; As[ac8 + 1][ar] = v0.y;
        As[ac8 + 2][ar] = v0.z; As[ac8 + 3][ar] = v0.w;
        As[ac8 + 4][ar] = v1.x; As[ac8 + 5][ar] = v1.y;
        As[ac8 + 6][ar] = v1.z; As[ac8 + 7][ar] = v1.w;
    }

    // this thread's 4 row ids (src/dst), hoisted across tiles
    int rs[4], rd[4];
#pragma unroll
    for (int i = 0; i < 4; i++) {
        int j = min(m0 + ty * 4 + i, count - 1);
        rs[i] = srcv ? srcv[j] : j;
        rd[i] = dstv ? dstv[j] : j;
    }

    // prefetch tile-0 gathers
    float4 ga[4], gb[4];
#pragma unroll
    for (int i = 0; i < 4; i++) {
        ga[i] = *(const float4*)(xl + (size_t)rs[i] * C + tx * 4);
        gb[i] = *(const float4*)(xr + (size_t)rd[i] * C + tx * 4);
    }

    float p[4] = {0.f, 0.f, 0.f, 0.f};

    for (int n0 = 0; n0 < C; n0 += 64) {
        // stage B tile: We[32][C] cols n0..n0+63
        {
            int br = tid >> 3, bc8 = (tid & 7) << 3;
            const float* s = We + (size_t)br * C + n0 + bc8;
            *(float4*)&Bs[br][bc8] = *(const float4*)s;
            *(float4*)&Bs[br][bc8 + 4] = *(const float4*)(s + 4);
        }
        __syncthreads();

        // issue NEXT tile's gathers; GEMM below hides their latency
        float4 na[4], nb[4];
        if (n0 + 64 < C) {
#pragma unroll
            for (int i = 0; i < 4; i++) {
                na[i] = *(const float4*)(xl + (size_t)rs[i] * C + n0 + 64 + tx * 4);
                nb[i] = *(const float4*)(xr + (size_t)rd[i] * C + n0 + 64 + tx * 4);
            }
        }

        float acc[4][4] = {};
#pragma unroll
        for (int k = 0; k < ED; k++) {
            float4 av = *(const float4*)&As[k][ty * 4];
            float4 bv = *(const float4*)&Bs[k][tx * 4];
            float a[4] = {av.x, av.y, av.z, av.w};
            float b[4] = {bv.x, bv.y, bv.z, bv.w};
#pragma unroll
            for (int i = 0; i < 4; i++)
#pragma unroll
                for (int j = 0; j < 4; j++) acc[i][j] = fmaf(a[i], b[j], acc[i][j]);
        }

        float attv[4];
#pragma unroll
        for (int j = 0; j < 4; j++) attv[j] = att[n0 + tx * 4 + j];
#pragma unroll
        for (int i = 0; i < 4; i++) {
            float xs4[4] = {ga[i].x + gb[i].x, ga[i].y + gb[i].y,
                            ga[i].z + gb[i].z, ga[i].w + gb[i].w};
#pragma unroll
            for (int j = 0; j < 4; j++) {
                float v = acc[i][j] + xs4[j];
                v = v > 0.f ? v : 0.2f * v;
                p[i] = fmaf(v, attv[j], p[i]);
            }
        }
        __syncthreads();  // before Bs overwrite next tile
        if (n0 + 64 < C) {
#pragma unroll
            for (int i = 0; i < 4; i++) { ga[i] = na[i]; gb[i] = nb[i]; }
        }
    }

#pragma unroll
    for (int i = 0; i < 4; i++) {
        float q = p[i];
        q += __shfl_xor(q, 1);
        q += __shfl_xor(q, 2);
        q += __shfl_xor(q, 4);
        q += __shfl_xor(q, 8);
        int r = m0 + ty * 4 + i;
        if (tx == 0 && r < count) sc_out[r] = q;
    }
}

// ---------------- aggregate: softmax over precomputed scores + pipelined gather ----------
template <int C>
__global__ __launch_bounds__(256) void aggregate2_kernel(
    const int* __restrict__ row_start, const int* __restrict__ srcv,
    const float* __restrict__ scores, const float* __restrict__ sscore,
    const float* __restrict__ xl, const float* __restrict__ bias,
    float* __restrict__ xout) {
    constexpr int VP = C / 64;
    const int wave = threadIdx.x >> 6, lane = threadIdx.x & 63;
    const int i = blockIdx.x * 4 + wave;
    if (i >= Nn) return;
    const int r0 = row_start[i], r1 = row_start[i + 1];

    // max over incoming + self
    float mx = sscore[i];
    for (int j = r0 + lane; j < r1; j += 64) mx = fmaxf(mx, scores[j]);
#pragma unroll
    for (int off = 32; off >= 1; off >>= 1) mx = fmaxf(mx, __shfl_xor(mx, off));

    float l = 0.f;
    float acc[VP];
#pragma unroll
    for (int j = 0; j < VP; j++) acc[j] = 0.f;

    float wA[4], xA[4][VP];
    auto load_batch = [&](int j0, float* w, float (*x)[VP]) {
#pragma unroll
        for (int q = 0; q < 4; q++) {
            int j = min(j0 + q, r1 - 1);
            w[q] = scores[j];
            const float* p = xl + (size_t)srcv[j] * C + lane * VP;
            if constexpr (VP == 4) {
                float4 v = *(const float4*)p;
                x[q][0] = v.x; x[q][1] = v.y; x[q][2] = v.z; x[q][3] = v.w;
            } else {
                float2 v = *(const float2*)p;
                x[q][0] = v.x; x[q][1] = v.y;
            }
        }
    };
    if (r0 < r1) load_batch(r0, wA, xA);

    for (int j0 = r0; j0 < r1; j0 += 4) {
        float wB[4], xB[4][VP];
        if (j0 + 4 < r1) load_batch(j0 + 4, wB, xB);  // prefetch next batch
        const int nb = min(4, r1 - j0);
        for (int q = 0; q < nb; q++) {
            float w = __expf(wA[q] - mx);
            l += w;
#pragma unroll
            for (int j = 0; j < VP; j++) acc[j] = fmaf(w, xA[q][j], acc[j]);
        }
        if (j0 + 4 < r1) {
#pragma unroll
            for (int q = 0; q < 4; q++) {
                wA[q] = wB[q];
#pragma unroll
                for (int j = 0; j < VP; j++) xA[q][j] = xB[q][j];
            }
        }
    }

    // self-loop
    {
        float w = __expf(sscore[i] - mx);
        l += w;
        const float* p = xl + (size_t)i * C + lane * VP;
        if constexpr (VP == 4) {
            float4 v = *(const float4*)p;
            acc[0] = fmaf(w, v.x, acc[0]); acc[1] = fmaf(w, v.y, acc[1]);
            acc[2] = fmaf(w, v.z, acc[2]); acc[3] = fmaf(w, v.w, acc[3]);
        } else {
            float2 v = *(const float2*)p;
            acc[0] = fmaf(w, v.x, acc[0]); acc[1] = fmaf(w, v.y, acc[1]);
        }
    }

    float invl = 1.0f / l;
    float* xo = xout + (size_t)i * C + lane * VP;
    if constexpr (VP == 4) {
        float4 bv = *(const float4*)(bias + lane * 4);
        float4 o;
        o.x = fmaxf(fmaf(acc[0], invl, bv.x), 0.f);
        o.y = fmaxf(fmaf(acc[1], invl, bv.y), 0.f);
        o.z = fmaxf(fmaf(acc[2], invl, bv.z), 0.f);
        o.w = fmaxf(fmaf(acc[3], invl, bv.w), 0.f);
        *(float4*)xo = o;
    } else {
        float2 bv = *(const float2*)(bias + lane * 2);
        float2 o;
        o.x = fmaxf(fmaf(acc[0], invl, bv.x), 0.f);
        o.y = fmaxf(fmaf(acc[1], invl, bv.y), 0.f);
        *(float2*)xo = o;
    }
}

// ---------------- global mean pool: run-length accumulation (batch is sorted) -------------
__global__ __launch_bounds__(128) void pool2_kernel(const float* __restrict__ x2,
                                                    const int* __restrict__ batch,
                                                    float* __restrict__ pooled,
                                                    float* __restrict__ cnt) {
    const int c = threadIdx.x;  // column 0..127
    const int chunk = (Nn + gridDim.x - 1) / gridDim.x;
    int lo = blockIdx.x * chunk;
    int hi = min(lo + chunk, Nn);
    if (lo >= hi) return;
    int gcur = batch[lo];
    float acc = 0.f, ncnt = 0.f;
    for (int i = lo; i < hi; i++) {
        int g = batch[i];
        if (g != gcur) {
            atomicAdd(&pooled[gcur * H2 + c], acc);
            if (c == 0) atomicAdd(&cnt[gcur], ncnt);
            acc = 0.f; ncnt = 0.f; gcur = g;
        }
        acc += x2[(size_t)i * H2 + c];
        ncnt += 1.f;
    }
    atomicAdd(&pooled[gcur * H2 + c], acc);
    if (c == 0) atomicAdd(&cnt[gcur], ncnt);
}

// ---------------- MLP head ----------------
__global__ __launch_bounds__(64) void head_kernel(
    const float* __restrict__ pooled, const float* __restrict__ cnt,
    const float* __restrict__ Wd1, const float* __restrict__ bd1,
    const float* __restrict__ gamma, const float* __restrict__ beta,
    const float* __restrict__ mean, const float* __restrict__ var,
    const float* __restrict__ Wd2, const float* __restrict__ bd2,
    float* __restrict__ out) {
    __shared__ float xm[H2];
    __shared__ float h[HD];
    int g = blockIdx.x, t = threadIdx.x;
    float c = fmaxf(cnt[g], 1.0f);
    for (int i = t; i < H2; i += 64) xm[i] = pooled[g * H2 + i] / c;
    __syncthreads();
    float a = bd1[t];
    for (int k = 0; k < H2; k++) a = fmaf(xm[k], Wd1[k * HD + t], a);
    a = (a - mean[t]) / sqrtf(var[t] + 1e-5f) * gamma[t] + beta[t];
    a = a > 0.f ? a : 0.1f * a;
    h[t] = a;
    __syncthreads();
    if (t < NOUT) {
        float o = bd2[t];
        for (int k = 0; k < HD; k++) o = fmaf(h[k], Wd2[k * NOUT + t], o);
        out[g * NOUT + t] = o;
    }
}

extern "C" void kernel_launch(void* const* d_in, const int* in_sizes, int n_in,
                              void* d_out, int out_size, void* d_ws, size_t ws_size,
                              hipStream_t stream) {
    const float* node_attr = (const float*)d_in[0];
    const float* edge_attr = (const float*)d_in[1];
    const int* edge_src = (const int*)d_in[2];
    const int* edge_dst = (const int*)d_in[3];
    const int* batch = (const int*)d_in[4];
    const float* Wl1 = (const float*)d_in[5];  const float* bl1 = (const float*)d_in[6];
    const float* Wr1 = (const float*)d_in[7];  const float* br1 = (const float*)d_in[8];
    const float* We1 = (const float*)d_in[9];  const float* att1 = (const float*)d_in[10];
    const float* b1 = (const float*)d_in[11];
    const float* Wl2 = (const float*)d_in[12]; const float* bl2 = (const float*)d_in[13];
    const float* Wr2 = (const float*)d_in[14]; const float* br2 = (const float*)d_in[15];
    const float* We2 = (const float*)d_in[16]; const float* att2 = (const float*)d_in[17];
    const float* b2 = (const float*)d_in[18];
    const float* Wd1 = (const float*)d_in[19]; const float* bd1 = (const float*)d_in[20];
    const float* bn_gamma = (const float*)d_in[21]; const float* bn_beta = (const float*)d_in[22];
    const float* bn_mean = (const float*)d_in[23];  const float* bn_var = (const float*)d_in[24];
    const float* Wd2 = (const float*)d_in[25]; const float* bd2 = (const float*)d_in[26];
    float* out = (float*)d_out;

    char* ws = (char*)d_ws;
    size_t off = 0;
    auto alloc = [&](size_t bytes) -> char* {
        char* p = ws + off;
        off = (off + bytes + 255) & ~(size_t)255;
        return p;
    };
    int* deg         = (int*)alloc((size_t)Nn * 4);
    int* row_start   = (int*)alloc((size_t)(Nn + 1) * 4);
    int* cursor      = (int*)alloc((size_t)Nn * 4);
    int* perm        = (int*)alloc((size_t)Ne * 4);
    int* srcv        = (int*)alloc((size_t)Ne * 4);
    int* dstv        = (int*)alloc((size_t)Ne * 4);
    float* loop_attr = (float*)alloc((size_t)Nn * ED * 4);
    float* scores    = (float*)alloc((size_t)Ne * 4);
    float* sscore    = (float*)alloc((size_t)Nn * 4);
    float* pooled    = (float*)alloc((size_t)Gg * H2 * 4);
    float* cnt       = (float*)alloc((size_t)Gg * 4);
    float* xlb       = (float*)alloc((size_t)Nn * H1 * 4);
    float* xrb       = (float*)alloc((size_t)Nn * H1 * 4);
    float* x1        = (float*)alloc((size_t)Nn * H1 * 4);

    hipMemsetAsync(deg, 0, (size_t)Nn * 4, stream);
    hipMemsetAsync(cursor, 0, (size_t)Nn * 4, stream);
    hipMemsetAsync(pooled, 0, (size_t)Gg * H2 * 4, stream);
    hipMemsetAsync(cnt, 0, (size_t)Gg * 4, stream);

    count_deg_kernel<<<(Ne + 255) / 256, 256, 0, stream>>>(edge_dst, deg);
    scan_kernel<<<1, 1024, 0, stream>>>(deg, row_start);
    scatter_kernel<<<(Ne + 255) / 256, 256, 0, stream>>>(edge_dst, row_start, cursor, perm);
    build_sd_kernel<<<(Ne + 255) / 256, 256, 0, stream>>>(perm, edge_src, edge_dst, srcv, dstv);
    loop_attr_kernel<<<(Nn * 8 + 255) / 256, 256, 0, stream>>>(row_start, perm, edge_attr, loop_attr);

    const int eb = (Ne + 63) / 64, nbk = (Nn + 63) / 64;

    // ---- layer 1 ----
    gemm_bias2_kernel<<<dim3(H1 / 64, (Nn + 63) / 64, 2), 256, 0, stream>>>(
        node_attr, Wl1, bl1, xlb, Wr1, br1, xrb, Nn, DIN, H1);
    score_gemm3_kernel<H1><<<eb, 256, 0, stream>>>(
        Ne, perm, srcv, dstv, edge_attr, xlb, xrb, We1, att1, scores);
    score_gemm3_kernel<H1><<<nbk, 256, 0, stream>>>(
        Nn, nullptr, nullptr, nullptr, loop_attr, xlb, xrb, We1, att1, sscore);
    aggregate2_kernel<H1><<<(Nn + 3) / 4, 256, 0, stream>>>(
        row_start, srcv, scores, sscore, xlb, b1, x1);

    // ---- layer 2 ----
    gemm_bias2_kernel<<<dim3(H2 / 64, (Nn + 63) / 64, 2), 256, 0, stream>>>(
        x1, Wl2, bl2, xlb, Wr2, br2, xrb, Nn, H1, H2);
    score_gemm3_kernel<H2><<<eb, 256, 0, stream>>>(
        Ne, perm, srcv, dstv, edge_attr, xlb, xrb, We2, att2, scores);
    score_gemm3_kernel<H2><<<nbk, 256, 0, stream>>>(
        Nn, nullptr, nullptr, nullptr, loop_attr, xlb, xrb, We2, att2, sscore);
    float* x2 = x1;
    aggregate2_kernel<H2><<<(Nn + 3) / 4, 256, 0, stream>>>(
        row_start, srcv, scores, sscore, xlb, b2, x2);

    // ---- pool + head ----
    pool2_kernel<<<256, 128, 0, stream>>>(x2, batch, pooled, cnt);
    head_kernel<<<Gg, 64, 0, stream>>>(pooled, cnt, Wd1, bd1, bn_gamma, bn_beta,
                                       bn_mean, bn_var, Wd2, bd2, out);
}

// Round 10
// 915.280 us; speedup vs baseline: 1.0560x; 1.0560x over previous
//
#include <hip/hip_runtime.h>
#include <cstdint>
#include <cstddef>

// Problem constants (match reference)
constexpr int Nn = 50000;
constexpr int Ne = 500000;
constexpr int Gg = 64;
constexpr int DIN = 128, ED = 32, H1 = 256, H2 = 128, HD = 64, NOUT = 8;

// ---------------- CSR build ----------------
__global__ void count_deg_kernel(const int* __restrict__ dst, int* __restrict__ deg) {
    int e = blockIdx.x * 256 + threadIdx.x;
    if (e < Ne) atomicAdd(&deg[dst[e]], 1);
}

__global__ __launch_bounds__(1024) void scan_kernel(const int* __restrict__ deg,
                                                    int* __restrict__ row_start) {
    __shared__ int part[1024];
    int t = threadIdx.x;
    const int chunk = (Nn + 1023) / 1024;
    int lo = t * chunk;
    int hi = min(lo + chunk, Nn);
    int s = 0;
    for (int i = lo; i < hi; i++) s += deg[i];
    part[t] = s;
    __syncthreads();
    for (int off = 1; off < 1024; off <<= 1) {
        int add = (t >= off) ? part[t - off] : 0;
        __syncthreads();
        part[t] += add;
        __syncthreads();
    }
    int base = (t == 0) ? 0 : part[t - 1];
    for (int i = lo; i < hi; i++) { row_start[i] = base; base += deg[i]; }
    if (t == 0) row_start[Nn] = Ne;
}

__global__ void scatter_kernel(const int* __restrict__ dst, const int* __restrict__ row_start,
                               int* __restrict__ cursor, int* __restrict__ perm) {
    int e = blockIdx.x * 256 + threadIdx.x;
    if (e < Ne) {
        int d = dst[e];
        int p = atomicAdd(&cursor[d], 1);
        perm[row_start[d] + p] = e;
    }
}

__global__ void build_sd_kernel(const int* __restrict__ perm, const int* __restrict__ src,
                                const int* __restrict__ dst,
                                int* __restrict__ srcv, int* __restrict__ dstv) {
    int j = blockIdx.x * 256 + threadIdx.x;
    if (j < Ne) {
        int e = perm[j];
        srcv[j] = src[e];
        dstv[j] = dst[e];
    }
}

// loop_attr[i] = mean of incoming edge_attr rows (self-loop fill_value='mean')
__global__ void loop_attr_kernel(const int* __restrict__ row_start, const int* __restrict__ perm,
                                 const float* __restrict__ eattr, float* __restrict__ loop_attr) {
    int tid = blockIdx.x * 256 + threadIdx.x;
    if (tid >= Nn * 8) return;
    int i = tid >> 3, q = (tid & 7) << 2;
    int r0 = row_start[i], r1 = row_start[i + 1];
    float4 s = make_float4(0.f, 0.f, 0.f, 0.f);
    for (int j = r0; j < r1; j++) {
        int e = perm[j];
        float4 v = *(const float4*)(eattr + (size_t)e * ED + q);
        s.x += v.x; s.y += v.y; s.z += v.z; s.w += v.w;
    }
    float inv = 1.0f / fmaxf((float)(r1 - r0), 1.0f);
    *(float4*)(loop_attr + (size_t)i * ED + q) =
        make_float4(s.x * inv, s.y * inv, s.z * inv, s.w * inv);
}

// ---------------- fp32 GEMM with K-chunk register double-buffer (kept from R9: helped) ----
__global__ __launch_bounds__(256) void gemm_bias2_kernel(const float* __restrict__ A,
                                                         const float* __restrict__ W0,
                                                         const float* __restrict__ bias0,
                                                         float* __restrict__ C0,
                                                         const float* __restrict__ W1,
                                                         const float* __restrict__ bias1,
                                                         float* __restrict__ C1,
                                                         int M, int K, int Ncols) {
    const float* W = blockIdx.z ? W1 : W0;
    const float* bias = blockIdx.z ? bias1 : bias0;
    float* C = blockIdx.z ? C1 : C0;
    __shared__ float As[16][68];  // [k][m], padded
    __shared__ float Bs[16][68];  // [k][n], padded
    const int m0 = blockIdx.y * 64, n0 = blockIdx.x * 64;
    const int tid = threadIdx.x;
    const int tx = tid & 15, ty = tid >> 4;
    float acc[4][4] = {};
    const int ar = tid >> 2, ac4 = (tid & 3) << 2;
    const int br = tid >> 4, bc4 = (tid & 15) << 2;
    const bool arow_ok = (m0 + ar < M);

    float4 av = make_float4(0.f, 0.f, 0.f, 0.f);
    if (arow_ok) av = *(const float4*)(A + (size_t)(m0 + ar) * K + ac4);
    float4 bv = *(const float4*)(W + (size_t)br * Ncols + n0 + bc4);

    for (int k0 = 0; k0 < K; k0 += 16) {
        As[ac4 + 0][ar] = av.x; As[ac4 + 1][ar] = av.y;
        As[ac4 + 2][ar] = av.z; As[ac4 + 3][ar] = av.w;
        *(float4*)&Bs[br][bc4] = bv;
        __syncthreads();
        // prefetch next chunk behind the FMA loop
        if (k0 + 16 < K) {
            if (arow_ok) av = *(const float4*)(A + (size_t)(m0 + ar) * K + k0 + 16 + ac4);
            bv = *(const float4*)(W + (size_t)(k0 + 16 + br) * Ncols + n0 + bc4);
        }
#pragma unroll
        for (int k = 0; k < 16; k++) {
            float a[4], b[4];
#pragma unroll
            for (int i = 0; i < 4; i++) a[i] = As[k][ty * 4 + i];
#pragma unroll
            for (int j = 0; j < 4; j++) b[j] = Bs[k][tx * 4 + j];
#pragma unroll
            for (int i = 0; i < 4; i++)
#pragma unroll
                for (int j = 0; j < 4; j++) acc[i][j] = fmaf(a[i], b[j], acc[i][j]);
        }
        __syncthreads();
    }
#pragma unroll
    for (int i = 0; i < 4; i++) {
        int m = m0 + ty * 4 + i;
        if (m < M) {
            float4 o;
            o.x = acc[i][0] + bias[n0 + tx * 4 + 0];
            o.y = acc[i][1] + bias[n0 + tx * 4 + 1];
            o.z = acc[i][2] + bias[n0 + tx * 4 + 2];
            o.w = acc[i][3] + bias[n0 + tx * 4 + 3];
            *(float4*)(C + (size_t)m * Ncols + n0 + tx * 4) = o;
        }
    }
}

// ---------------- score GEMM v2 (R8 version, reverted from v3): occupancy > prefetch ------
// R9 lesson: prefetching xl/xr across tiles doubled VGPR 48->96, Occ 49->22%, dur 142->189us.
// This kernel is occupancy-limited; keep VGPR at 48 and let inter-wave overlap hide latency.
template <int C>
__global__ __launch_bounds__(256) void score_gemm2_kernel(
    int count, const int* __restrict__ perm,
    const int* __restrict__ srcv, const int* __restrict__ dstv,
    const float* __restrict__ attr,
    const float* __restrict__ xl, const float* __restrict__ xr,
    const float* __restrict__ We, const float* __restrict__ att,
    float* __restrict__ sc_out) {
    __shared__ float As[32][68];   // eattr^T [k][row]
    __shared__ float Bs[32][68];   // We tile [k][col]
    const int m0 = blockIdx.x * 64;
    const int tid = threadIdx.x, tx = tid & 15, ty = tid >> 4;

    // stage A^T once: 64 rows x 32 k
    {
        int ar = tid >> 2, ac8 = (tid & 3) << 3;
        int row = min(m0 + ar, count - 1);
        int e = perm ? perm[row] : row;
        const float* s = attr + (size_t)e * ED + ac8;
        float4 v0 = *(const float4*)s;
        float4 v1 = *(const float4*)(s + 4);
        As[ac8 + 0][ar] = v0.x; As[ac8 + 1][ar] = v0.y;
        As[ac8 + 2][ar] = v0.z; As[ac8 + 3][ar] = v0.w;
        As[ac8 + 4][ar] = v1.x; As[ac8 + 5][ar] = v1.y;
        As[ac8 + 6][ar] = v1.z; As[ac8 + 7][ar] = v1.w;
    }

    // this thread's 4 row ids (src/dst), hoisted across tiles
    int rs[4], rd[4];
#pragma unroll
    for (int i = 0; i < 4; i++) {
        int j = min(m0 + ty * 4 + i, count - 1);
        rs[i] = srcv ? srcv[j] : j;
        rd[i] = dstv ? dstv[j] : j;
    }

    float p[4] = {0.f, 0.f, 0.f, 0.f};

    for (int n0 = 0; n0 < C; n0 += 64) {
        // stage B tile: We[32][C] cols n0..n0+63
        {
            int br = tid >> 3, bc8 = (tid & 7) << 3;
            const float* s = We + (size_t)br * C + n0 + bc8;
            *(float4*)&Bs[br][bc8] = *(const float4*)s;
            *(float4*)&Bs[br][bc8 + 4] = *(const float4*)(s + 4);
        }
        __syncthreads();

        float acc[4][4] = {};
#pragma unroll
        for (int k = 0; k < ED; k++) {
            float4 av = *(const float4*)&As[k][ty * 4];
            float4 bv = *(const float4*)&Bs[k][tx * 4];
            float a[4] = {av.x, av.y, av.z, av.w};
            float b[4] = {bv.x, bv.y, bv.z, bv.w};
#pragma unroll
            for (int i = 0; i < 4; i++)
#pragma unroll
                for (int j = 0; j < 4; j++) acc[i][j] = fmaf(a[i], b[j], acc[i][j]);
        }

        float attv[4];
#pragma unroll
        for (int j = 0; j < 4; j++) attv[j] = att[n0 + tx * 4 + j];
#pragma unroll
        for (int i = 0; i < 4; i++) {
            float4 a4 = *(const float4*)(xl + (size_t)rs[i] * C + n0 + tx * 4);
            float4 b4 = *(const float4*)(xr + (size_t)rd[i] * C + n0 + tx * 4);
            float xs4[4] = {a4.x + b4.x, a4.y + b4.y, a4.z + b4.z, a4.w + b4.w};
#pragma unroll
            for (int j = 0; j < 4; j++) {
                float v = acc[i][j] + xs4[j];
                v = v > 0.f ? v : 0.2f * v;
                p[i] = fmaf(v, attv[j], p[i]);
            }
        }
        __syncthreads();  // before Bs overwrite next tile
    }

#pragma unroll
    for (int i = 0; i < 4; i++) {
        float q = p[i];
        q += __shfl_xor(q, 1);
        q += __shfl_xor(q, 2);
        q += __shfl_xor(q, 4);
        q += __shfl_xor(q, 8);
        int r = m0 + ty * 4 + i;
        if (tx == 0 && r < count) sc_out[r] = q;
    }
}

// ---------------- aggregate: softmax over precomputed scores + pipelined gather ----------
template <int C>
__global__ __launch_bounds__(256) void aggregate2_kernel(
    const int* __restrict__ row_start, const int* __restrict__ srcv,
    const float* __restrict__ scores, const float* __restrict__ sscore,
    const float* __restrict__ xl, const float* __restrict__ bias,
    float* __restrict__ xout) {
    constexpr int VP = C / 64;
    const int wave = threadIdx.x >> 6, lane = threadIdx.x & 63;
    const int i = blockIdx.x * 4 + wave;
    if (i >= Nn) return;
    const int r0 = row_start[i], r1 = row_start[i + 1];

    // max over incoming + self
    float mx = sscore[i];
    for (int j = r0 + lane; j < r1; j += 64) mx = fmaxf(mx, scores[j]);
#pragma unroll
    for (int off = 32; off >= 1; off >>= 1) mx = fmaxf(mx, __shfl_xor(mx, off));

    float l = 0.f;
    float acc[VP];
#pragma unroll
    for (int j = 0; j < VP; j++) acc[j] = 0.f;

    float wA[4], xA[4][VP];
    auto load_batch = [&](int j0, float* w, float (*x)[VP]) {
#pragma unroll
        for (int q = 0; q < 4; q++) {
            int j = min(j0 + q, r1 - 1);
            w[q] = scores[j];
            const float* p = xl + (size_t)srcv[j] * C + lane * VP;
            if constexpr (VP == 4) {
                float4 v = *(const float4*)p;
                x[q][0] = v.x; x[q][1] = v.y; x[q][2] = v.z; x[q][3] = v.w;
            } else {
                float2 v = *(const float2*)p;
                x[q][0] = v.x; x[q][1] = v.y;
            }
        }
    };
    if (r0 < r1) load_batch(r0, wA, xA);

    for (int j0 = r0; j0 < r1; j0 += 4) {
        float wB[4], xB[4][VP];
        if (j0 + 4 < r1) load_batch(j0 + 4, wB, xB);  // prefetch next batch
        const int nb = min(4, r1 - j0);
        for (int q = 0; q < nb; q++) {
            float w = __expf(wA[q] - mx);
            l += w;
#pragma unroll
            for (int j = 0; j < VP; j++) acc[j] = fmaf(w, xA[q][j], acc[j]);
        }
        if (j0 + 4 < r1) {
#pragma unroll
            for (int q = 0; q < 4; q++) {
                wA[q] = wB[q];
#pragma unroll
                for (int j = 0; j < VP; j++) xA[q][j] = xB[q][j];
            }
        }
    }

    // self-loop
    {
        float w = __expf(sscore[i] - mx);
        l += w;
        const float* p = xl + (size_t)i * C + lane * VP;
        if constexpr (VP == 4) {
            float4 v = *(const float4*)p;
            acc[0] = fmaf(w, v.x, acc[0]); acc[1] = fmaf(w, v.y, acc[1]);
            acc[2] = fmaf(w, v.z, acc[2]); acc[3] = fmaf(w, v.w, acc[3]);
        } else {
            float2 v = *(const float2*)p;
            acc[0] = fmaf(w, v.x, acc[0]); acc[1] = fmaf(w, v.y, acc[1]);
        }
    }

    float invl = 1.0f / l;
    float* xo = xout + (size_t)i * C + lane * VP;
    if constexpr (VP == 4) {
        float4 bv = *(const float4*)(bias + lane * 4);
        float4 o;
        o.x = fmaxf(fmaf(acc[0], invl, bv.x), 0.f);
        o.y = fmaxf(fmaf(acc[1], invl, bv.y), 0.f);
        o.z = fmaxf(fmaf(acc[2], invl, bv.z), 0.f);
        o.w = fmaxf(fmaf(acc[3], invl, bv.w), 0.f);
        *(float4*)xo = o;
    } else {
        float2 bv = *(const float2*)(bias + lane * 2);
        float2 o;
        o.x = fmaxf(fmaf(acc[0], invl, bv.x), 0.f);
        o.y = fmaxf(fmaf(acc[1], invl, bv.y), 0.f);
        *(float2*)xo = o;
    }
}

// ---------------- global mean pool: run-length accumulation (batch is sorted) -------------
__global__ __launch_bounds__(128) void pool2_kernel(const float* __restrict__ x2,
                                                    const int* __restrict__ batch,
                                                    float* __restrict__ pooled,
                                                    float* __restrict__ cnt) {
    const int c = threadIdx.x;  // column 0..127
    const int chunk = (Nn + gridDim.x - 1) / gridDim.x;
    int lo = blockIdx.x * chunk;
    int hi = min(lo + chunk, Nn);
    if (lo >= hi) return;
    int gcur = batch[lo];
    float acc = 0.f, ncnt = 0.f;
    for (int i = lo; i < hi; i++) {
        int g = batch[i];
        if (g != gcur) {
            atomicAdd(&pooled[gcur * H2 + c], acc);
            if (c == 0) atomicAdd(&cnt[gcur], ncnt);
            acc = 0.f; ncnt = 0.f; gcur = g;
        }
        acc += x2[(size_t)i * H2 + c];
        ncnt += 1.f;
    }
    atomicAdd(&pooled[gcur * H2 + c], acc);
    if (c == 0) atomicAdd(&cnt[gcur], ncnt);
}

// ---------------- MLP head ----------------
__global__ __launch_bounds__(64) void head_kernel(
    const float* __restrict__ pooled, const float* __restrict__ cnt,
    const float* __restrict__ Wd1, const float* __restrict__ bd1,
    const float* __restrict__ gamma, const float* __restrict__ beta,
    const float* __restrict__ mean, const float* __restrict__ var,
    const float* __restrict__ Wd2, const float* __restrict__ bd2,
    float* __restrict__ out) {
    __shared__ float xm[H2];
    __shared__ float h[HD];
    int g = blockIdx.x, t = threadIdx.x;
    float c = fmaxf(cnt[g], 1.0f);
    for (int i = t; i < H2; i += 64) xm[i] = pooled[g * H2 + i] / c;
    __syncthreads();
    float a = bd1[t];
    for (int k = 0; k < H2; k++) a = fmaf(xm[k], Wd1[k * HD + t], a);
    a = (a - mean[t]) / sqrtf(var[t] + 1e-5f) * gamma[t] + beta[t];
    a = a > 0.f ? a : 0.1f * a;
    h[t] = a;
    __syncthreads();
    if (t < NOUT) {
        float o = bd2[t];
        for (int k = 0; k < HD; k++) o = fmaf(h[k], Wd2[k * NOUT + t], o);
        out[g * NOUT + t] = o;
    }
}

extern "C" void kernel_launch(void* const* d_in, const int* in_sizes, int n_in,
                              void* d_out, int out_size, void* d_ws, size_t ws_size,
                              hipStream_t stream) {
    const float* node_attr = (const float*)d_in[0];
    const float* edge_attr = (const float*)d_in[1];
    const int* edge_src = (const int*)d_in[2];
    const int* edge_dst = (const int*)d_in[3];
    const int* batch = (const int*)d_in[4];
    const float* Wl1 = (const float*)d_in[5];  const float* bl1 = (const float*)d_in[6];
    const float* Wr1 = (const float*)d_in[7];  const float* br1 = (const float*)d_in[8];
    const float* We1 = (const float*)d_in[9];  const float* att1 = (const float*)d_in[10];
    const float* b1 = (const float*)d_in[11];
    const float* Wl2 = (const float*)d_in[12]; const float* bl2 = (const float*)d_in[13];
    const float* Wr2 = (const float*)d_in[14]; const float* br2 = (const float*)d_in[15];
    const float* We2 = (const float*)d_in[16]; const float* att2 = (const float*)d_in[17];
    const float* b2 = (const float*)d_in[18];
    const float* Wd1 = (const float*)d_in[19]; const float* bd1 = (const float*)d_in[20];
    const float* bn_gamma = (const float*)d_in[21]; const float* bn_beta = (const float*)d_in[22];
    const float* bn_mean = (const float*)d_in[23];  const float* bn_var = (const float*)d_in[24];
    const float* Wd2 = (const float*)d_in[25]; const float* bd2 = (const float*)d_in[26];
    float* out = (float*)d_out;

    char* ws = (char*)d_ws;
    size_t off = 0;
    auto alloc = [&](size_t bytes) -> char* {
        char* p = ws + off;
        off = (off + bytes + 255) & ~(size_t)255;
        return p;
    };
    int* deg         = (int*)alloc((size_t)Nn * 4);
    int* row_start   = (int*)alloc((size_t)(Nn + 1) * 4);
    int* cursor      = (int*)alloc((size_t)Nn * 4);
    int* perm        = (int*)alloc((size_t)Ne * 4);
    int* srcv        = (int*)alloc((size_t)Ne * 4);
    int* dstv        = (int*)alloc((size_t)Ne * 4);
    float* loop_attr = (float*)alloc((size_t)Nn * ED * 4);
    float* scores    = (float*)alloc((size_t)Ne * 4);
    float* sscore    = (float*)alloc((size_t)Nn * 4);
    float* pooled    = (float*)alloc((size_t)Gg * H2 * 4);
    float* cnt       = (float*)alloc((size_t)Gg * 4);
    float* xlb       = (float*)alloc((size_t)Nn * H1 * 4);
    float* xrb       = (float*)alloc((size_t)Nn * H1 * 4);
    float* x1        = (float*)alloc((size_t)Nn * H1 * 4);

    hipMemsetAsync(deg, 0, (size_t)Nn * 4, stream);
    hipMemsetAsync(cursor, 0, (size_t)Nn * 4, stream);
    hipMemsetAsync(pooled, 0, (size_t)Gg * H2 * 4, stream);
    hipMemsetAsync(cnt, 0, (size_t)Gg * 4, stream);

    count_deg_kernel<<<(Ne + 255) / 256, 256, 0, stream>>>(edge_dst, deg);
    scan_kernel<<<1, 1024, 0, stream>>>(deg, row_start);
    scatter_kernel<<<(Ne + 255) / 256, 256, 0, stream>>>(edge_dst, row_start, cursor, perm);
    build_sd_kernel<<<(Ne + 255) / 256, 256, 0, stream>>>(perm, edge_src, edge_dst, srcv, dstv);
    loop_attr_kernel<<<(Nn * 8 + 255) / 256, 256, 0, stream>>>(row_start, perm, edge_attr, loop_attr);

    const int eb = (Ne + 63) / 64, nbk = (Nn + 63) / 64;

    // ---- layer 1 ----
    gemm_bias2_kernel<<<dim3(H1 / 64, (Nn + 63) / 64, 2), 256, 0, stream>>>(
        node_attr, Wl1, bl1, xlb, Wr1, br1, xrb, Nn, DIN, H1);
    score_gemm2_kernel<H1><<<eb, 256, 0, stream>>>(
        Ne, perm, srcv, dstv, edge_attr, xlb, xrb, We1, att1, scores);
    score_gemm2_kernel<H1><<<nbk, 256, 0, stream>>>(
        Nn, nullptr, nullptr, nullptr, loop_attr, xlb, xrb, We1, att1, sscore);
    aggregate2_kernel<H1><<<(Nn + 3) / 4, 256, 0, stream>>>(
        row_start, srcv, scores, sscore, xlb, b1, x1);

    // ---- layer 2 ----
    gemm_bias2_kernel<<<dim3(H2 / 64, (Nn + 63) / 64, 2), 256, 0, stream>>>(
        x1, Wl2, bl2, xlb, Wr2, br2, xrb, Nn, H1, H2);
    score_gemm2_kernel<H2><<<eb, 256, 0, stream>>>(
        Ne, perm, srcv, dstv, edge_attr, xlb, xrb, We2, att2, scores);
    score_gemm2_kernel<H2><<<nbk, 256, 0, stream>>>(
        Nn, nullptr, nullptr, nullptr, loop_attr, xlb, xrb, We2, att2, sscore);
    float* x2 = x1;
    aggregate2_kernel<H2><<<(Nn + 3) / 4, 256, 0, stream>>>(
        row_start, srcv, scores, sscore, xlb, b2, x2);

    // ---- pool + head ----
    pool2_kernel<<<256, 128, 0, stream>>>(x2, batch, pooled, cnt);
    head_kernel<<<Gg, 64, 0, stream>>>(pooled, cnt, Wd1, bd1, bn_gamma, bn_beta,
                                       bn_mean, bn_var, Wd2, bd2, out);
}